// Round 4
// baseline (351.279 us; speedup 1.0000x reference)
//
#include <hip/hip_runtime.h>
#include <hip/hip_bf16.h>

#define BB 512
#define SS 1024
#define DIN 64
#define HH 64
#define SD4 4
#define CH 64     // scan chunk length
#define LB 64     // scan lookback (0.925^64 = 6.8e-3 decay of init error)

typedef __attribute__((ext_vector_type(8))) short s8v;   // 8 bf16 (4 VGPRs)
typedef __attribute__((ext_vector_type(4))) float f4v;   // MFMA accumulator

#define MFMA_BF16(a, b, c) __builtin_amdgcn_mfma_f32_16x16x32_bf16((a), (b), (c), 0, 0, 0)

// DPP cross-lane move in the VALU pipe. ctrl: 0x00-0xFF quad_perm; 0x120+N row_ror:N.
template <int CTRL>
__device__ __forceinline__ float dppf(float v) {
    return __int_as_float(__builtin_amdgcn_mov_dpp(__float_as_int(v), CTRL, 0xF, 0xF, false));
}

__device__ __forceinline__ float rcp_fast(float x) {
    return __builtin_amdgcn_rcpf(x);   // v_rcp_f32: 1 instr, ~1 ulp
}
// HW packed f32->bf16 (RNE), 2 elements per instruction.
__device__ __forceinline__ unsigned int cvt_pk(float lo, float hi) {
    unsigned int r;
    asm("v_cvt_pk_bf16_f32 %0, %1, %2" : "=v"(r) : "v"(lo), "v"(hi));
    return r;
}
__device__ __forceinline__ float bf2f(unsigned short u) {
    return __uint_as_float(((unsigned int)u) << 16);
}
__device__ __forceinline__ float sigmoid_f(float x) {
    return 1.0f / (1.0f + __expf(-x));
}
__device__ __forceinline__ float tanh_fast(float x) {
    return fmaf(-2.0f, rcp_fast(__expf(2.0f * x) + 1.0f), 1.0f);
}
__device__ __forceinline__ float gelu_fast(float x) {
    // tanh-form GELU as x*sigmoid(-z)
    float x2 = x * x;
    float z = x * fmaf(x2, -0.0713548162f, -1.5957691216f);
    return x * rcp_fast(1.0f + __expf(z));
}
__device__ __forceinline__ s8v cvt8(const float* __restrict__ p) {
    const float4* q4 = (const float4*)p;
    float4 a = q4[0], b = q4[1];
    union { s8v s; unsigned int u[4]; } r;
    r.u[0] = cvt_pk(a.x, a.y); r.u[1] = cvt_pk(a.z, a.w);
    r.u[2] = cvt_pk(b.x, b.y); r.u[3] = cvt_pk(b.z, b.w);
    return r.s;
}

// ---------------------------------------------------------------------------
// Phase 1 (MFMA): byte-identical to R3/R7 (clock-corrected they measured the
// same; FETCH/WRITE 66/74 MB). pre4 layout token-blocked by 4:
//   uint2 pre4[(T>>2)*64 + L*4 + (T&3)]; lane L holds units {L,L+16|L+32,L+48}.
// ---------------------------------------------------------------------------
__global__ __launch_bounds__(256)
void prep_mfma(const float* __restrict__ x,
               const float* __restrict__ W1, const float* __restrict__ b1,
               const float* __restrict__ ln_g, const float* __restrict__ ln_b,
               const float* __restrict__ Wi, const float* __restrict__ bi,
               const float* __restrict__ Wc1, const float* __restrict__ bc1,
               uint2* __restrict__ pre4, float* __restrict__ bx)
{
    __shared__ unsigned short hb[4][16 * 88];  // h transpose, per wave
    __shared__ unsigned short wcs[64 * 72];    // Wc1[:,4:68] bf16, stride 72

    const int tid = threadIdx.x;
    const int wave = tid >> 6;
    const int lane = tid & 63;
    const int c = lane & 15;
    const int q = lane >> 4;

    const long tokW = ((long)blockIdx.x * 4 + wave) * 64;

    // tile-0 A-fragment prefetch: issue before weight staging so the first
    // vmcnt wait overlaps all of the setup below.
    const float* xp = x + (tokW + c) * DIN + q * 8;
    float4 xf0 = *(const float4*)(xp + 0);
    float4 xf1 = *(const float4*)(xp + 4);
    float4 xf2 = *(const float4*)(xp + 32);
    float4 xf3 = *(const float4*)(xp + 36);
    xp += 16 * DIN;

    // stage Wc1[:,4:68] -> LDS bf16 (block-cooperative, one barrier total)
    {
        const int row = tid >> 2, chn = tid & 3;
        const float4* s4 = (const float4*)(Wc1 + row * 68 + 4 + chn * 16);
        float4 f0 = s4[0], f1 = s4[1], f2 = s4[2], f3 = s4[3];
        uint2* dst = (uint2*)(wcs + row * 72 + chn * 16);
        dst[0] = make_uint2(cvt_pk(f0.x, f0.y), cvt_pk(f0.z, f0.w));
        dst[1] = make_uint2(cvt_pk(f1.x, f1.y), cvt_pk(f1.z, f1.w));
        dst[2] = make_uint2(cvt_pk(f2.x, f2.y), cvt_pk(f2.z, f2.w));
        dst[3] = make_uint2(cvt_pk(f3.x, f3.y), cvt_pk(f3.z, f3.w));
    }
    __syncthreads();

    // GEMM1 B-fragments: col c <- W1 row (4c+n)  [permuted: contiguous h]
    s8v W1f[4][2], Wif[2];
#pragma unroll
    for (int n = 0; n < 4; ++n)
#pragma unroll
        for (int kh = 0; kh < 2; ++kh)
            W1f[n][kh] = cvt8(W1 + (4 * c + n) * DIN + q * 8 + kh * 32);
#pragma unroll
    for (int kh = 0; kh < 2; ++kh) {
        if (c < 4) {
            Wif[kh] = cvt8(Wi + c * HH + q * 8 + kh * 32);
        } else {
            s8v z;
#pragma unroll
            for (int e = 0; e < 8; ++e) z[e] = 0;
            Wif[kh] = z;
        }
    }

    float gln[4], bln[4], b1v[4], bc1v[4];
#pragma unroll
    for (int n = 0; n < 4; ++n) {
        const int j1 = 4 * c + n;      // GEMM1 output unit for acc[n]
        const int j2 = c + 16 * n;     // GEMM2 output unit for p[n]
        gln[n] = ln_g[j1]; bln[n] = ln_b[j1]; b1v[n] = b1[j1];
        bc1v[n] = bc1[j2];
    }
    const float biv = (c < 4) ? bi[c] : 0.0f;

    unsigned short* Hb = hb[wave];
    uint2* pq = pre4 + ((tokW >> 2) + q) * 64 + c * 4;
    float* bq = bx + (tokW + q * 4) * SD4 + c;

    // GEMM1 + LN + GELU for one tile: pure VALU/DPP/MFMA, no DS ops.
    auto gemm1_ln = [&](s8v A0_, s8v A1_, uint2* hwo) {
        f4v acc[4];
#pragma unroll
        for (int n = 0; n < 4; ++n) {
            f4v z = { b1v[n], b1v[n], b1v[n], b1v[n] };   // bias via C-in
            z = MFMA_BF16(A0_, W1f[n][0], z);
            acc[n] = MFMA_BF16(A1_, W1f[n][1], z);
        }
        // LN stats (sum over all 64 units = 4 local + 16-lane row_ror chain)
        float sm[4], sq[4];
#pragma unroll
        for (int r = 0; r < 4; ++r) {
            sm[r] = acc[0][r] + acc[1][r] + acc[2][r] + acc[3][r];
            sq[r] = fmaf(acc[0][r], acc[0][r],
                    fmaf(acc[1][r], acc[1][r],
                    fmaf(acc[2][r], acc[2][r], acc[3][r] * acc[3][r])));
        }
#pragma unroll
        for (int r = 0; r < 4; ++r) { sm[r] += dppf<0x121>(sm[r]); sq[r] += dppf<0x121>(sq[r]); }
#pragma unroll
        for (int r = 0; r < 4; ++r) { sm[r] += dppf<0x122>(sm[r]); sq[r] += dppf<0x122>(sq[r]); }
#pragma unroll
        for (int r = 0; r < 4; ++r) { sm[r] += dppf<0x124>(sm[r]); sq[r] += dppf<0x124>(sq[r]); }
#pragma unroll
        for (int r = 0; r < 4; ++r) { sm[r] += dppf<0x128>(sm[r]); sq[r] += dppf<0x128>(sq[r]); }
#pragma unroll
        for (int r = 0; r < 4; ++r) {
            const float mu = sm[r] * (1.0f / HH);
            const float var = fmaf(-mu, mu, sq[r] * (1.0f / HH));
            const float rstd = rsqrtf(var + 1e-5f);
            float g0 = gelu_fast(fmaf((acc[0][r] - mu) * rstd, gln[0], bln[0]));
            float g1 = gelu_fast(fmaf((acc[1][r] - mu) * rstd, gln[1], bln[1]));
            float g2 = gelu_fast(fmaf((acc[2][r] - mu) * rstd, gln[2], bln[2]));
            float g3 = gelu_fast(fmaf((acc[3][r] - mu) * rstd, gln[3], bln[3]));
            hwo[r] = make_uint2(cvt_pk(g0, g1), cvt_pk(g2, g3));
        }
    };

    // ---- prologue: tile 0 through GEMM1, h(0) into hb ----
    s8v A0, A1;
    {
        union { s8v s; unsigned int u[4]; } a;
        a.u[0] = cvt_pk(xf0.x, xf0.y); a.u[1] = cvt_pk(xf0.z, xf0.w);
        a.u[2] = cvt_pk(xf1.x, xf1.y); a.u[3] = cvt_pk(xf1.z, xf1.w);
        A0 = a.s;
        a.u[0] = cvt_pk(xf2.x, xf2.y); a.u[1] = cvt_pk(xf2.z, xf2.w);
        a.u[2] = cvt_pk(xf3.x, xf3.y); a.u[3] = cvt_pk(xf3.z, xf3.w);
        A1 = a.s;
    }
    // prefetch tile-1 fragments (hidden under GEMM1(0))
    xf0 = *(const float4*)(xp + 0);
    xf1 = *(const float4*)(xp + 4);
    xf2 = *(const float4*)(xp + 32);
    xf3 = *(const float4*)(xp + 36);
    xp += 16 * DIN;

    uint2 hw[4];
    gemm1_ln(A0, A1, hw);
#pragma unroll
    for (int r = 0; r < 4; ++r) *(uint2*)(Hb + (q * 4 + r) * 88 + 4 * c) = hw[r];

    // ---- pipelined main loop ----
#pragma unroll 1
    for (int t = 0; t < 4; ++t) {
        // issue H(t) reads first; GEMM1(t+1) below has no DS ops, so their
        // lgkm latency hides under ~500 cyc of VALU before GEMM2 uses them.
        s8v H0 = *(const s8v*)(Hb + c * 88 + q * 8);
        s8v H1 = *(const s8v*)(Hb + c * 88 + 32 + q * 8);

        uint2 hwn[4];
        if (t < 3) {
            union { s8v s; unsigned int u[4]; } a;
            a.u[0] = cvt_pk(xf0.x, xf0.y); a.u[1] = cvt_pk(xf0.z, xf0.w);
            a.u[2] = cvt_pk(xf1.x, xf1.y); a.u[3] = cvt_pk(xf1.z, xf1.w);
            s8v nA0 = a.s;
            a.u[0] = cvt_pk(xf2.x, xf2.y); a.u[1] = cvt_pk(xf2.z, xf2.w);
            a.u[2] = cvt_pk(xf3.x, xf3.y); a.u[3] = cvt_pk(xf3.z, xf3.w);
            s8v nA1 = a.s;
            if (t < 2) {  // prefetch tile t+2
                xf0 = *(const float4*)(xp + 0);
                xf1 = *(const float4*)(xp + 4);
                xf2 = *(const float4*)(xp + 32);
                xf3 = *(const float4*)(xp + 36);
                xp += 16 * DIN;
            }
            gemm1_ln(nA0, nA1, hwn);
        }

        // GEMM2 (tile t): Wc1 fragments from shared LDS (stride-72 rows)
        f4v p[4];
#pragma unroll
        for (int n = 0; n < 4; ++n) {
            const s8v Wf0 = *(const s8v*)(wcs + (c + 16 * n) * 72 + q * 8);
            const s8v Wf1 = *(const s8v*)(wcs + (c + 16 * n) * 72 + 32 + q * 8);
            f4v z = { bc1v[n], bc1v[n], bc1v[n], bc1v[n] };   // bias via C-in
            z = MFMA_BF16(H0, Wf0, z);
            p[n] = MFMA_BF16(H1, Wf1, z);
        }
        f4v bz = { biv, biv, biv, biv };
        bz = MFMA_BF16(H0, Wif[0], bz);
        bz = MFMA_BF16(H1, Wif[1], bz);

        if (c < 4) {
#pragma unroll
            for (int r = 0; r < 4; ++r) bq[r * SD4] = bz[r];
        }
        {
            uint2 u0 = make_uint2(cvt_pk(p[0][0], p[1][0]), cvt_pk(p[2][0], p[3][0]));
            uint2 u1 = make_uint2(cvt_pk(p[0][1], p[1][1]), cvt_pk(p[2][1], p[3][1]));
            uint2 u2 = make_uint2(cvt_pk(p[0][2], p[1][2]), cvt_pk(p[2][2], p[3][2]));
            uint2 u3 = make_uint2(cvt_pk(p[0][3], p[1][3]), cvt_pk(p[2][3], p[3][3]));
            *(uint4*)(pq)     = make_uint4(u0.x, u0.y, u1.x, u1.y);
            *(uint4*)(pq + 2) = make_uint4(u2.x, u2.y, u3.x, u3.y);
        }
        pq += 256; bq += 64;

        // h(t+1) -> hb AFTER the H(t)/Wf reads (per-wave in-order DS => safe)
        if (t < 3) {
#pragma unroll
            for (int r = 0; r < 4; ++r) *(uint2*)(Hb + (q * 4 + r) * 88 + 4 * c) = hwn[r];
        }
    }
}

// ---------------------------------------------------------------------------
// Phase 2 V3: two independent chunk-chains PER 16-LANE GROUP (ILP=2).
//  - 512 blocks (one batch each) x 128 threads; group g (tid>>4, 0..7) runs
//    chunks {g, g+8} of batch blockIdx.x interleaved in registers.
//  - Rationale: scan was latency-bound at 2 waves/SIMD (~520 cyc/step vs
//    ~140 issue floor). Chain-pair ILP doubles per-wave issue density AND
//    doubles the TIME depth of the 8-step register prefetch (~2240 cyc
//    > ~900 cyc HBM latency) with zero extra traffic.
//  - core4 is compute-only (returns parked output); both chains' bodies sit
//    in one branch-free region so the scheduler interleaves their chains.
//  - Even/odd register-set naming: set freed at iteration k is refilled with
//    slot k+8's data (period-2 queue, no rotation moves, all static indexing).
// Per-step arithmetic bit-identical to R3.
// ---------------------------------------------------------------------------
__global__ __launch_bounds__(128)
void scan_chunk(const uint2* __restrict__ pre4, const float* __restrict__ bx,
                const float* __restrict__ Wc1, const float* __restrict__ Wc2,
                const float* __restrict__ bc2, const float* __restrict__ corr_scale,
                const float* __restrict__ A_level, const float* __restrict__ A_trend,
                const float* __restrict__ A_gamma, const float* __restrict__ A_resid,
                const float* __restrict__ omega, float* __restrict__ out)
{
    const int tid = threadIdx.x;
    const int g = tid >> 4;          // 0..7: chunk pair {g, g+8}
    const int L = tid & 15;
    const int b = blockIdx.x;        // batch
    const int cA = g, cB = g + 8;
    const int warmA = (cA == 0) ? 0 : LB;
    const int t0A = cA * CH - warmA;
    const int t0B = cB * CH - LB;    // warmB == LB always

    float w[4][4], v[4][4];
#pragma unroll
    for (int m = 0; m < 4; ++m) {
        const int j = L + 16 * m;
#pragma unroll
        for (int k = 0; k < 4; ++k) {
            w[m][k] = Wc1[j * 68 + k];
            v[k][m] = Wc2[k * HH + j];
        }
    }
    const float cs = corr_scale[0];
    const float a0 = sigmoid_f(A_level[0]) * 0.15f + 0.85f;
    const float a1 = sigmoid_f(A_trend[0]) * 0.25f + 0.70f;
    const float a2 = (sigmoid_f(A_gamma[0]) * 0.2f + 0.8f) * cosf(omega[0]);
    const float a3 = sigmoid_f(A_resid[0]) * 0.4f;
    const float csel = bc2[L & 3];
    const bool o1 = (L & 1) != 0;
    const bool o2 = (L & 2) != 0;
    const int myi = L >> 2;

    const uint4* ppA = (const uint4*)pre4 + (((long)b * SS + t0A) >> 2) * 32 + L * 2;
    const uint4* ppB = (const uint4*)pre4 + (((long)b * SS + t0B) >> 2) * 32 + L * 2;
    const float4* bpA = (const float4*)bx + (long)b * SS + t0A;
    const float4* bpB = (const float4*)bx + (long)b * SS + t0B;
    float* opA = out + ((long)b * SS + t0A) * SD4;
    float* opB = out + ((long)b * SS + t0B) * SD4;

    float As0 = 0.f, As1 = 0.f, As2 = 0.f, As3 = 0.f;
    float Bs0 = 0.f, Bs1 = 0.f, Bs2 = 0.f, Bs3 = 0.f;

    // 4 scan steps; compute-only, returns parked output value for this lane.
    auto core4 = [&](const uint4& qa, const uint4& qb,
                     const float4& bv0, const float4& bv1,
                     const float4& bv2, const float4& bv3,
                     float& s0, float& s1, float& s2, float& s3) -> float {
        float oreg = 0.f;
#pragma unroll
        for (int i = 0; i < 4; ++i) {
            const unsigned int ux = (i == 0) ? qa.x : (i == 1) ? qa.z : (i == 2) ? qb.x : qb.z;
            const unsigned int uy = (i == 0) ? qa.y : (i == 1) ? qa.w : (i == 2) ? qb.y : qb.w;
            const float4 bv = (i == 0) ? bv0 : (i == 1) ? bv1 : (i == 2) ? bv2 : bv3;
            const float l0 = fmaf(a0, s0, bv.x);
            const float l1 = fmaf(a1, s1, bv.y);
            const float l2 = fmaf(a2, s2, bv.z);
            const float l3 = fmaf(a3, s3, bv.w);
            const float p0 = bf2f((unsigned short)(ux & 0xffffu));
            const float p1 = bf2f((unsigned short)(ux >> 16));
            const float p2 = bf2f((unsigned short)(uy & 0xffffu));
            const float p3 = bf2f((unsigned short)(uy >> 16));
            float gg[4];
            {
                float ua0 = fmaf(l0, w[0][0], p0), ub0 = fmaf(l2, w[0][2], l3 * w[0][3]);
                float ua1 = fmaf(l0, w[1][0], p1), ub1 = fmaf(l2, w[1][2], l3 * w[1][3]);
                float ua2 = fmaf(l0, w[2][0], p2), ub2 = fmaf(l2, w[2][2], l3 * w[2][3]);
                float ua3 = fmaf(l0, w[3][0], p3), ub3 = fmaf(l2, w[3][2], l3 * w[3][3]);
                gg[0] = gelu_fast(fmaf(l1, w[0][1], ua0) + ub0);
                gg[1] = gelu_fast(fmaf(l1, w[1][1], ua1) + ub1);
                gg[2] = gelu_fast(fmaf(l1, w[2][1], ua2) + ub2);
                gg[3] = gelu_fast(fmaf(l1, w[3][1], ua3) + ub3);
            }
            const float P0 = fmaf(gg[0], v[0][0], gg[1] * v[0][1]) + fmaf(gg[2], v[0][2], gg[3] * v[0][3]);
            const float P1 = fmaf(gg[0], v[1][0], gg[1] * v[1][1]) + fmaf(gg[2], v[1][2], gg[3] * v[1][3]);
            const float P2 = fmaf(gg[0], v[2][0], gg[1] * v[2][1]) + fmaf(gg[2], v[2][2], gg[3] * v[2][3]);
            const float P3 = fmaf(gg[0], v[3][0], gg[1] * v[3][1]) + fmaf(gg[2], v[3][2], gg[3] * v[3][3]);
            const float k0 = o1 ? P1 : P0, s0s = o1 ? P0 : P1;
            const float k1 = o1 ? P3 : P2, s1s = o1 ? P2 : P3;
            const float Af = k0 + dppf<0xB1>(s0s);   // quad_perm xor 1
            const float Bf = k1 + dppf<0xB1>(s1s);
            const float kk = o2 ? Bf : Af, ss = o2 ? Af : Bf;
            float T = kk + dppf<0x4E>(ss);           // quad_perm xor 2
            T += dppf<0x124>(T);                     // row_ror:4
            T += dppf<0x128>(T);                     // row_ror:8
            const float th = tanh_fast(T + csel);
            const float lsel = o2 ? (o1 ? l3 : l2) : (o1 ? l1 : l0);
            const float sval = fmaf(cs, th, lsel);
            s0 = dppf<0x00>(sval);
            s1 = dppf<0x55>(sval);
            s2 = dppf<0xAA>(sval);
            s3 = dppf<0xFF>(sval);
            if (myi == i) oreg = sval;               // park for coalesced store
        }
        return oreg;
    };

    auto refill = [&](uint4& qa, uint4& qb, float4& bv0, float4& bv1,
                      float4& bv2, float4& bv3,
                      const uint4* pp, const float4* bp, int pf) {
        const uint4* p = pp + (pf >> 2) * 32;
        qa = p[0]; qb = p[1];
        bv0 = bp[pf]; bv1 = bp[pf + 1]; bv2 = bp[pf + 2]; bv3 = bp[pf + 3];
    };

    // even/odd register sets per chain: E holds slot it, O holds slot it+4
    uint4 EAqa, EAqb, OAqa, OAqb, EBqa, EBqb, OBqa, OBqb;
    float4 EAb0, EAb1, EAb2, EAb3, OAb0, OAb1, OAb2, OAb3;
    float4 EBb0, EBb1, EBb2, EBb3, OBb0, OBb1, OBb2, OBb3;
    refill(EAqa, EAqb, EAb0, EAb1, EAb2, EAb3, ppA, bpA, 0);
    refill(EBqa, EBqb, EBb0, EBb1, EBb2, EBb3, ppB, bpB, 0);
    refill(OAqa, OAqb, OAb0, OAb1, OAb2, OAb3, ppA, bpA, 4);
    refill(OBqa, OBqb, OBb0, OBb1, OBb2, OBb3, ppB, bpB, 4);

#pragma unroll 1
    for (int it = 0; it < 2 * CH; it += 8) {
        const int pfE = (it + 8  < 2 * CH) ? (it + 8)  : (2 * CH - 4);
        const int pfO = (it + 12 < 2 * CH) ? (it + 12) : (2 * CH - 4);

        // ---- even slot (steps it..it+3), both chains in one region ----
        const float oAe = core4(EAqa, EAqb, EAb0, EAb1, EAb2, EAb3, As0, As1, As2, As3);
        const float oBe = core4(EBqa, EBqb, EBb0, EBb1, EBb2, EBb3, Bs0, Bs1, Bs2, Bs3);
        if ((unsigned)(it - warmA) < (unsigned)CH) opA[it * SD4 + L] = oAe;
        if (it >= LB)                              opB[it * SD4 + L] = oBe;
        // refill E sets with slot it+8 (consumed 2 iterations of 4-step slots later)
        refill(EAqa, EAqb, EAb0, EAb1, EAb2, EAb3, ppA, bpA, pfE);
        refill(EBqa, EBqb, EBb0, EBb1, EBb2, EBb3, ppB, bpB, pfE);

        // ---- odd slot (steps it+4..it+7) ----
        const float oAo = core4(OAqa, OAqb, OAb0, OAb1, OAb2, OAb3, As0, As1, As2, As3);
        const float oBo = core4(OBqa, OBqb, OBb0, OBb1, OBb2, OBb3, Bs0, Bs1, Bs2, Bs3);
        if ((unsigned)(it + 4 - warmA) < (unsigned)CH) opA[(it + 4) * SD4 + L] = oAo;
        if (it + 4 >= LB)                              opB[(it + 4) * SD4 + L] = oBo;
        refill(OAqa, OAqb, OAb0, OAb1, OAb2, OAb3, ppA, bpA, pfO);
        refill(OBqa, OBqb, OBb0, OBb1, OBb2, OBb3, ppB, bpB, pfO);
    }
}

extern "C" void kernel_launch(void* const* d_in, const int* in_sizes, int n_in,
                              void* d_out, int out_size, void* d_ws, size_t ws_size,
                              hipStream_t stream) {
    (void)in_sizes; (void)n_in; (void)out_size; (void)ws_size;
    const float* x    = (const float*)d_in[0];
    const float* W1   = (const float*)d_in[1];
    const float* b1   = (const float*)d_in[2];
    const float* ln_g = (const float*)d_in[3];
    const float* ln_b = (const float*)d_in[4];
    const float* Wi   = (const float*)d_in[5];
    const float* bi   = (const float*)d_in[6];
    const float* Wc1  = (const float*)d_in[7];
    const float* bc1  = (const float*)d_in[8];
    const float* Wc2  = (const float*)d_in[9];
    const float* bc2  = (const float*)d_in[10];
    const float* corr = (const float*)d_in[11];
    const float* Al   = (const float*)d_in[12];
    const float* At   = (const float*)d_in[13];
    const float* Ag   = (const float*)d_in[14];
    const float* Ar   = (const float*)d_in[15];
    const float* om   = (const float*)d_in[16];

    uint2* pre4 = (uint2*)d_ws;  // 512*1024*16 uint2 = 64 MiB
    float* bx = (float*)((char*)d_ws + (size_t)BB * SS * 16 * sizeof(uint2)); // 8 MiB
    float* out = (float*)d_out;

    prep_mfma<<<dim3(2048), dim3(256), 0, stream>>>(
        x, W1, b1, ln_g, ln_b, Wi, bi, Wc1, bc1, pre4, bx);
    scan_chunk<<<dim3(BB), dim3(128), 0, stream>>>(
        pre4, bx, Wc1, Wc2, bc2, corr, Al, At, Ag, Ar, om, out);
}

// Round 5
// 295.906 us; speedup vs baseline: 1.1871x; 1.1871x over previous
//
#include <hip/hip_runtime.h>
#include <hip/hip_bf16.h>

#define BB 512
#define SS 1024
#define DIN 64
#define HH 64
#define SD4 4
#define CH 64     // scan chunk length
#define LB 64     // scan lookback (0.925^64 = 6.8e-3 decay of init error)

typedef __attribute__((ext_vector_type(8))) short s8v;   // 8 bf16 (4 VGPRs)
typedef __attribute__((ext_vector_type(4))) float f4v;   // MFMA accumulator

#define MFMA_BF16(a, b, c) __builtin_amdgcn_mfma_f32_16x16x32_bf16((a), (b), (c), 0, 0, 0)

// DPP cross-lane move in the VALU pipe. ctrl: 0x00-0xFF quad_perm; 0x120+N row_ror:N.
template <int CTRL>
__device__ __forceinline__ float dppf(float v) {
    return __int_as_float(__builtin_amdgcn_mov_dpp(__float_as_int(v), CTRL, 0xF, 0xF, false));
}

__device__ __forceinline__ float rcp_fast(float x) {
    return __builtin_amdgcn_rcpf(x);   // v_rcp_f32: 1 instr, ~1 ulp
}
// HW packed f32->bf16 (RNE), 2 elements per instruction.
__device__ __forceinline__ unsigned int cvt_pk(float lo, float hi) {
    unsigned int r;
    asm("v_cvt_pk_bf16_f32 %0, %1, %2" : "=v"(r) : "v"(lo), "v"(hi));
    return r;
}
__device__ __forceinline__ float sigmoid_f(float x) {
    return 1.0f / (1.0f + __expf(-x));
}
__device__ __forceinline__ float tanh_fast(float x) {
    return fmaf(-2.0f, rcp_fast(__expf(2.0f * x) + 1.0f), 1.0f);
}
__device__ __forceinline__ float gelu_fast(float x) {
    // tanh-form GELU as x*sigmoid(-z)
    float x2 = x * x;
    float z = x * fmaf(x2, -0.0713548162f, -1.5957691216f);
    return x * rcp_fast(1.0f + __expf(z));
}
__device__ __forceinline__ s8v cvt8(const float* __restrict__ p) {
    const float4* q4 = (const float4*)p;
    float4 a = q4[0], b = q4[1];
    union { s8v s; unsigned int u[4]; } r;
    r.u[0] = cvt_pk(a.x, a.y); r.u[1] = cvt_pk(a.z, a.w);
    r.u[2] = cvt_pk(b.x, b.y); r.u[3] = cvt_pk(b.z, b.w);
    return r.s;
}

// ---------------------------------------------------------------------------
// Phase 1 (MFMA): byte-identical to R3/R4. pre4 layout token-blocked by 4:
//   uint2 pre4[(T>>2)*64 + L*4 + (T&3)]; lane L holds units {L,L+16|L+32,L+48}.
// ---------------------------------------------------------------------------
__global__ __launch_bounds__(256)
void prep_mfma(const float* __restrict__ x,
               const float* __restrict__ W1, const float* __restrict__ b1,
               const float* __restrict__ ln_g, const float* __restrict__ ln_b,
               const float* __restrict__ Wi, const float* __restrict__ bi,
               const float* __restrict__ Wc1, const float* __restrict__ bc1,
               uint2* __restrict__ pre4, float* __restrict__ bx)
{
    __shared__ unsigned short hb[4][16 * 88];  // h transpose, per wave
    __shared__ unsigned short wcs[64 * 72];    // Wc1[:,4:68] bf16, stride 72

    const int tid = threadIdx.x;
    const int wave = tid >> 6;
    const int lane = tid & 63;
    const int c = lane & 15;
    const int q = lane >> 4;

    const long tokW = ((long)blockIdx.x * 4 + wave) * 64;

    // tile-0 A-fragment prefetch: issue before weight staging so the first
    // vmcnt wait overlaps all of the setup below.
    const float* xp = x + (tokW + c) * DIN + q * 8;
    float4 xf0 = *(const float4*)(xp + 0);
    float4 xf1 = *(const float4*)(xp + 4);
    float4 xf2 = *(const float4*)(xp + 32);
    float4 xf3 = *(const float4*)(xp + 36);
    xp += 16 * DIN;

    // stage Wc1[:,4:68] -> LDS bf16 (block-cooperative, one barrier total)
    {
        const int row = tid >> 2, chn = tid & 3;
        const float4* s4 = (const float4*)(Wc1 + row * 68 + 4 + chn * 16);
        float4 f0 = s4[0], f1 = s4[1], f2 = s4[2], f3 = s4[3];
        uint2* dst = (uint2*)(wcs + row * 72 + chn * 16);
        dst[0] = make_uint2(cvt_pk(f0.x, f0.y), cvt_pk(f0.z, f0.w));
        dst[1] = make_uint2(cvt_pk(f1.x, f1.y), cvt_pk(f1.z, f1.w));
        dst[2] = make_uint2(cvt_pk(f2.x, f2.y), cvt_pk(f2.z, f2.w));
        dst[3] = make_uint2(cvt_pk(f3.x, f3.y), cvt_pk(f3.z, f3.w));
    }
    __syncthreads();

    // GEMM1 B-fragments: col c <- W1 row (4c+n)  [permuted: contiguous h]
    s8v W1f[4][2], Wif[2];
#pragma unroll
    for (int n = 0; n < 4; ++n)
#pragma unroll
        for (int kh = 0; kh < 2; ++kh)
            W1f[n][kh] = cvt8(W1 + (4 * c + n) * DIN + q * 8 + kh * 32);
#pragma unroll
    for (int kh = 0; kh < 2; ++kh) {
        if (c < 4) {
            Wif[kh] = cvt8(Wi + c * HH + q * 8 + kh * 32);
        } else {
            s8v z;
#pragma unroll
            for (int e = 0; e < 8; ++e) z[e] = 0;
            Wif[kh] = z;
        }
    }

    float gln[4], bln[4], b1v[4], bc1v[4];
#pragma unroll
    for (int n = 0; n < 4; ++n) {
        const int j1 = 4 * c + n;      // GEMM1 output unit for acc[n]
        const int j2 = c + 16 * n;     // GEMM2 output unit for p[n]
        gln[n] = ln_g[j1]; bln[n] = ln_b[j1]; b1v[n] = b1[j1];
        bc1v[n] = bc1[j2];
    }
    const float biv = (c < 4) ? bi[c] : 0.0f;

    unsigned short* Hb = hb[wave];
    uint2* pq = pre4 + ((tokW >> 2) + q) * 64 + c * 4;
    float* bq = bx + (tokW + q * 4) * SD4 + c;

    // GEMM1 + LN + GELU for one tile: pure VALU/DPP/MFMA, no DS ops.
    auto gemm1_ln = [&](s8v A0_, s8v A1_, uint2* hwo) {
        f4v acc[4];
#pragma unroll
        for (int n = 0; n < 4; ++n) {
            f4v z = { b1v[n], b1v[n], b1v[n], b1v[n] };   // bias via C-in
            z = MFMA_BF16(A0_, W1f[n][0], z);
            acc[n] = MFMA_BF16(A1_, W1f[n][1], z);
        }
        // LN stats (sum over all 64 units = 4 local + 16-lane row_ror chain)
        float sm[4], sq[4];
#pragma unroll
        for (int r = 0; r < 4; ++r) {
            sm[r] = acc[0][r] + acc[1][r] + acc[2][r] + acc[3][r];
            sq[r] = fmaf(acc[0][r], acc[0][r],
                    fmaf(acc[1][r], acc[1][r],
                    fmaf(acc[2][r], acc[2][r], acc[3][r] * acc[3][r])));
        }
#pragma unroll
        for (int r = 0; r < 4; ++r) { sm[r] += dppf<0x121>(sm[r]); sq[r] += dppf<0x121>(sq[r]); }
#pragma unroll
        for (int r = 0; r < 4; ++r) { sm[r] += dppf<0x122>(sm[r]); sq[r] += dppf<0x122>(sq[r]); }
#pragma unroll
        for (int r = 0; r < 4; ++r) { sm[r] += dppf<0x124>(sm[r]); sq[r] += dppf<0x124>(sq[r]); }
#pragma unroll
        for (int r = 0; r < 4; ++r) { sm[r] += dppf<0x128>(sm[r]); sq[r] += dppf<0x128>(sq[r]); }
#pragma unroll
        for (int r = 0; r < 4; ++r) {
            const float mu = sm[r] * (1.0f / HH);
            const float var = fmaf(-mu, mu, sq[r] * (1.0f / HH));
            const float rstd = rsqrtf(var + 1e-5f);
            float g0 = gelu_fast(fmaf((acc[0][r] - mu) * rstd, gln[0], bln[0]));
            float g1 = gelu_fast(fmaf((acc[1][r] - mu) * rstd, gln[1], bln[1]));
            float g2 = gelu_fast(fmaf((acc[2][r] - mu) * rstd, gln[2], bln[2]));
            float g3 = gelu_fast(fmaf((acc[3][r] - mu) * rstd, gln[3], bln[3]));
            hwo[r] = make_uint2(cvt_pk(g0, g1), cvt_pk(g2, g3));
        }
    };

    // ---- prologue: tile 0 through GEMM1, h(0) into hb ----
    s8v A0, A1;
    {
        union { s8v s; unsigned int u[4]; } a;
        a.u[0] = cvt_pk(xf0.x, xf0.y); a.u[1] = cvt_pk(xf0.z, xf0.w);
        a.u[2] = cvt_pk(xf1.x, xf1.y); a.u[3] = cvt_pk(xf1.z, xf1.w);
        A0 = a.s;
        a.u[0] = cvt_pk(xf2.x, xf2.y); a.u[1] = cvt_pk(xf2.z, xf2.w);
        a.u[2] = cvt_pk(xf3.x, xf3.y); a.u[3] = cvt_pk(xf3.z, xf3.w);
        A1 = a.s;
    }
    // prefetch tile-1 fragments (hidden under GEMM1(0))
    xf0 = *(const float4*)(xp + 0);
    xf1 = *(const float4*)(xp + 4);
    xf2 = *(const float4*)(xp + 32);
    xf3 = *(const float4*)(xp + 36);
    xp += 16 * DIN;

    uint2 hw[4];
    gemm1_ln(A0, A1, hw);
#pragma unroll
    for (int r = 0; r < 4; ++r) *(uint2*)(Hb + (q * 4 + r) * 88 + 4 * c) = hw[r];

    // ---- pipelined main loop ----
#pragma unroll 1
    for (int t = 0; t < 4; ++t) {
        // issue H(t) reads first; GEMM1(t+1) below has no DS ops, so their
        // lgkm latency hides under ~500 cyc of VALU before GEMM2 uses them.
        s8v H0 = *(const s8v*)(Hb + c * 88 + q * 8);
        s8v H1 = *(const s8v*)(Hb + c * 88 + 32 + q * 8);

        uint2 hwn[4];
        if (t < 3) {
            union { s8v s; unsigned int u[4]; } a;
            a.u[0] = cvt_pk(xf0.x, xf0.y); a.u[1] = cvt_pk(xf0.z, xf0.w);
            a.u[2] = cvt_pk(xf1.x, xf1.y); a.u[3] = cvt_pk(xf1.z, xf1.w);
            s8v nA0 = a.s;
            a.u[0] = cvt_pk(xf2.x, xf2.y); a.u[1] = cvt_pk(xf2.z, xf2.w);
            a.u[2] = cvt_pk(xf3.x, xf3.y); a.u[3] = cvt_pk(xf3.z, xf3.w);
            s8v nA1 = a.s;
            if (t < 2) {  // prefetch tile t+2
                xf0 = *(const float4*)(xp + 0);
                xf1 = *(const float4*)(xp + 4);
                xf2 = *(const float4*)(xp + 32);
                xf3 = *(const float4*)(xp + 36);
                xp += 16 * DIN;
            }
            gemm1_ln(nA0, nA1, hwn);
        }

        // GEMM2 (tile t): Wc1 fragments from shared LDS (stride-72 rows)
        f4v p[4];
#pragma unroll
        for (int n = 0; n < 4; ++n) {
            const s8v Wf0 = *(const s8v*)(wcs + (c + 16 * n) * 72 + q * 8);
            const s8v Wf1 = *(const s8v*)(wcs + (c + 16 * n) * 72 + 32 + q * 8);
            f4v z = { bc1v[n], bc1v[n], bc1v[n], bc1v[n] };   // bias via C-in
            z = MFMA_BF16(H0, Wf0, z);
            p[n] = MFMA_BF16(H1, Wf1, z);
        }
        f4v bz = { biv, biv, biv, biv };
        bz = MFMA_BF16(H0, Wif[0], bz);
        bz = MFMA_BF16(H1, Wif[1], bz);

        if (c < 4) {
#pragma unroll
            for (int r = 0; r < 4; ++r) bq[r * SD4] = bz[r];
        }
        {
            uint2 u0 = make_uint2(cvt_pk(p[0][0], p[1][0]), cvt_pk(p[2][0], p[3][0]));
            uint2 u1 = make_uint2(cvt_pk(p[0][1], p[1][1]), cvt_pk(p[2][1], p[3][1]));
            uint2 u2 = make_uint2(cvt_pk(p[0][2], p[1][2]), cvt_pk(p[2][2], p[3][2]));
            uint2 u3 = make_uint2(cvt_pk(p[0][3], p[1][3]), cvt_pk(p[2][3], p[3][3]));
            *(uint4*)(pq)     = make_uint4(u0.x, u0.y, u1.x, u1.y);
            *(uint4*)(pq + 2) = make_uint4(u2.x, u2.y, u3.x, u3.y);
        }
        pq += 256; bq += 64;

        // h(t+1) -> hb AFTER the H(t)/Wf reads (per-wave in-order DS => safe)
        if (t < 3) {
#pragma unroll
            for (int r = 0; r < 4; ++r) *(uint2*)(Hb + (q * 4 + r) * 88 + 4 * c) = hwn[r];
        }
    }
}

// ---------------------------------------------------------------------------
// Phase 2 V4: R3 structure restored (issue-bound diagnosis), instruction diet.
//  - R4 ILP=2 regressed (VGPR squeeze -> AGPR-copy bloat, 1 wave/SIMD @43%
//    duty). Back to: block = batch, 16 groups x 16 lanes, 2 waves/SIMD.
//  - __launch_bounds__(256,2): VGPR cap 256 (grid is 2048 waves = 2/SIMD, so
//    registers are free up to 256) -> no spills, no AGPR traffic.
//  - u-computation: 4-deep fma chain folding p as accumulator (20->16 instr).
//  - bf16 unpack via u<<16 / u&0xffff0000 (2 instr per pair).
//  - Distance-8 ping-pong prefetch (E/O sets); per-step arithmetic otherwise
//    identical butterfly to R2/R3 (passed absmax 0.03125).
// ---------------------------------------------------------------------------
__global__ __launch_bounds__(256, 2)
void scan_chunk(const uint2* __restrict__ pre4, const float* __restrict__ bx,
                const float* __restrict__ Wc1, const float* __restrict__ Wc2,
                const float* __restrict__ bc2, const float* __restrict__ corr_scale,
                const float* __restrict__ A_level, const float* __restrict__ A_trend,
                const float* __restrict__ A_gamma, const float* __restrict__ A_resid,
                const float* __restrict__ omega, float* __restrict__ out)
{
    const int tid = threadIdx.x;
    const int g = tid >> 4;          // chunk index, group in block
    const int L = tid & 15;
    const int b = blockIdx.x;        // batch
    const int warm = (g == 0) ? 0 : LB;
    const int t0 = g * CH - warm;
    const int wend = warm + CH;      // write window [warm, wend)
    const int myi = L >> 2;          // which step of a 4-group this lane stores

    float w[4][4], v[4][4];
#pragma unroll
    for (int m = 0; m < 4; ++m) {
        const int j = L + 16 * m;
#pragma unroll
        for (int k = 0; k < 4; ++k) {
            w[m][k] = Wc1[j * 68 + k];
            v[k][m] = Wc2[k * HH + j];
        }
    }
    const float cs = corr_scale[0];
    const float a0 = sigmoid_f(A_level[0]) * 0.15f + 0.85f;
    const float a1 = sigmoid_f(A_trend[0]) * 0.25f + 0.70f;
    const float a2 = (sigmoid_f(A_gamma[0]) * 0.2f + 0.8f) * cosf(omega[0]);
    const float a3 = sigmoid_f(A_resid[0]) * 0.4f;
    const float csel = bc2[L & 3];
    const bool o1 = (L & 1) != 0;
    const bool o2 = (L & 2) != 0;

    // pre4 as uint4: group tt -> pp[(tt>>2)*32 + {0,1}]
    const uint4* pp = (const uint4*)pre4 + (((long)b * SS + t0) >> 2) * 32 + L * 2;
    const float4* bp = (const float4*)bx + (long)b * SS + t0;
    float* op = out + ((long)b * SS + t0) * SD4;

    float s0 = 0.f, s1 = 0.f, s2 = 0.f, s3 = 0.f;

    // 4 steps from one staged group: qa holds tokens {0,1}, qb {2,3}
    auto step4 = [&](const uint4& qa, const uint4& qb, const float4* bv, int tt) {
        float oreg = 0.f;
#pragma unroll
        for (int i = 0; i < 4; ++i) {
            const unsigned int ux = (i == 0) ? qa.x : (i == 1) ? qa.z : (i == 2) ? qb.x : qb.z;
            const unsigned int uy = (i == 0) ? qa.y : (i == 1) ? qa.w : (i == 2) ? qb.y : qb.w;
            const float l0 = fmaf(a0, s0, bv[i].x);
            const float l1 = fmaf(a1, s1, bv[i].y);
            const float l2 = fmaf(a2, s2, bv[i].z);
            const float l3 = fmaf(a3, s3, bv[i].w);
            const float p0 = __uint_as_float(ux << 16);
            const float p1 = __uint_as_float(ux & 0xffff0000u);
            const float p2 = __uint_as_float(uy << 16);
            const float p3 = __uint_as_float(uy & 0xffff0000u);
            // u = l.w + p as 4-deep fma chains (16 fma, 4 independent chains)
            const float gg0 = gelu_fast(fmaf(l0, w[0][0], fmaf(l1, w[0][1], fmaf(l2, w[0][2], fmaf(l3, w[0][3], p0)))));
            const float gg1 = gelu_fast(fmaf(l0, w[1][0], fmaf(l1, w[1][1], fmaf(l2, w[1][2], fmaf(l3, w[1][3], p1)))));
            const float gg2 = gelu_fast(fmaf(l0, w[2][0], fmaf(l1, w[2][1], fmaf(l2, w[2][2], fmaf(l3, w[2][3], p2)))));
            const float gg3 = gelu_fast(fmaf(l0, w[3][0], fmaf(l1, w[3][1], fmaf(l2, w[3][2], fmaf(l3, w[3][3], p3)))));
            const float P0 = fmaf(gg0, v[0][0], gg1 * v[0][1]) + fmaf(gg2, v[0][2], gg3 * v[0][3]);
            const float P1 = fmaf(gg0, v[1][0], gg1 * v[1][1]) + fmaf(gg2, v[1][2], gg3 * v[1][3]);
            const float P2 = fmaf(gg0, v[2][0], gg1 * v[2][1]) + fmaf(gg2, v[2][2], gg3 * v[2][3]);
            const float P3 = fmaf(gg0, v[3][0], gg1 * v[3][1]) + fmaf(gg2, v[3][2], gg3 * v[3][3]);
            const float k0 = o1 ? P1 : P0, s0s = o1 ? P0 : P1;
            const float k1 = o1 ? P3 : P2, s1s = o1 ? P2 : P3;
            const float Af = k0 + dppf<0xB1>(s0s);   // quad_perm xor 1
            const float Bf = k1 + dppf<0xB1>(s1s);
            const float kk = o2 ? Bf : Af, ss = o2 ? Af : Bf;
            float T = kk + dppf<0x4E>(ss);           // quad_perm xor 2
            T += dppf<0x124>(T);                     // row_ror:4
            T += dppf<0x128>(T);                     // row_ror:8
            const float th = tanh_fast(T + csel);
            const float lsel = o2 ? (o1 ? l3 : l2) : (o1 ? l1 : l0);
            const float sval = fmaf(cs, th, lsel);
            s0 = dppf<0x00>(sval);
            s1 = dppf<0x55>(sval);
            s2 = dppf<0xAA>(sval);
            s3 = dppf<0xFF>(sval);
            if (myi == i) oreg = sval;               // park for coalesced store
        }
        if (tt >= warm && tt < wend) op[tt * SD4 + L] = oreg;  // 64 B / group
    };

    // ---- prologue: stage groups tt=0 and tt=4 ----
    uint4 qa0 = pp[0],  qb0 = pp[1];
    uint4 qa1 = pp[32], qb1 = pp[33];
    float4 bA[4], bB[4];
#pragma unroll
    for (int i = 0; i < 4; ++i) { bA[i] = bp[i]; bB[i] = bp[4 + i]; }

#pragma unroll 1
    for (int tt = 0; tt < 2 * CH; tt += 8) {
        // prefetch groups tt+8, tt+12 (clamped; re-reads last group at tail)
        const int pf0 = (tt + 8  < 2 * CH) ? (tt + 8)  : (2 * CH - 8);
        const int pf1 = (tt + 12 < 2 * CH) ? (tt + 12) : (2 * CH - 8);
        const uint4* p0 = pp + (pf0 >> 2) * 32;
        const uint4* p1 = pp + (pf1 >> 2) * 32;
        uint4 nqa0 = p0[0], nqb0 = p0[1];
        uint4 nqa1 = p1[0], nqb1 = p1[1];
        float4 nbA[4], nbB[4];
#pragma unroll
        for (int i = 0; i < 4; ++i) { nbA[i] = bp[pf0 + i]; nbB[i] = bp[pf1 + i]; }

        step4(qa0, qb0, bA, tt);
        step4(qa1, qb1, bB, tt + 4);

        qa0 = nqa0; qb0 = nqb0; qa1 = nqa1; qb1 = nqb1;
#pragma unroll
        for (int i = 0; i < 4; ++i) { bA[i] = nbA[i]; bB[i] = nbB[i]; }
    }
}

extern "C" void kernel_launch(void* const* d_in, const int* in_sizes, int n_in,
                              void* d_out, int out_size, void* d_ws, size_t ws_size,
                              hipStream_t stream) {
    (void)in_sizes; (void)n_in; (void)out_size; (void)ws_size;
    const float* x    = (const float*)d_in[0];
    const float* W1   = (const float*)d_in[1];
    const float* b1   = (const float*)d_in[2];
    const float* ln_g = (const float*)d_in[3];
    const float* ln_b = (const float*)d_in[4];
    const float* Wi   = (const float*)d_in[5];
    const float* bi   = (const float*)d_in[6];
    const float* Wc1  = (const float*)d_in[7];
    const float* bc1  = (const float*)d_in[8];
    const float* Wc2  = (const float*)d_in[9];
    const float* bc2  = (const float*)d_in[10];
    const float* corr = (const float*)d_in[11];
    const float* Al   = (const float*)d_in[12];
    const float* At   = (const float*)d_in[13];
    const float* Ag   = (const float*)d_in[14];
    const float* Ar   = (const float*)d_in[15];
    const float* om   = (const float*)d_in[16];

    uint2* pre4 = (uint2*)d_ws;  // 512*1024*16 uint2 = 64 MiB
    float* bx = (float*)((char*)d_ws + (size_t)BB * SS * 16 * sizeof(uint2)); // 8 MiB
    float* out = (float*)d_out;

    prep_mfma<<<dim3(2048), dim3(256), 0, stream>>>(
        x, W1, b1, ln_g, ln_b, Wi, bi, Wc1, bc1, pre4, bx);
    scan_chunk<<<dim3(BB), dim3(256), 0, stream>>>(
        pre4, bx, Wc1, Wc2, bc2, corr, Al, At, Ag, Ar, om, out);
}